// Round 1
// baseline (140.123 us; speedup 1.0000x reference)
//
#include <hip/hip_runtime.h>

// VIN: only batch 0 reaches the output, HID=150 contracts into a 2x3x3 eff-conv,
// and the r-channel contribution to q (qr) is VI-iteration-invariant.
// Single workgroup (1024 threads, 1 CU): v,r in LDS, qr in registers,
// 19 sequential v-updates with __syncthreads (grid sync would cost more).

#define ACT   8
#define HID   150
#define NK    64
#define LDSW  67   // 66 would give 4-way LDS bank aliasing; 67 -> 2-way (free)

__launch_bounds__(1024)
__global__ void vin_kernel(const float* __restrict__ X,
                           const int*   __restrict__ S1,
                           const int*   __restrict__ S2,
                           const float* __restrict__ Wh,
                           const float* __restrict__ bh,
                           const float* __restrict__ Wr,
                           const float* __restrict__ Wq,
                           float*       __restrict__ out) {
  __shared__ float r_s[66][LDSW];   // 64x64 + 1-cell zero halo
  __shared__ float v_s[66][LDSW];
  __shared__ float weff_s[20];      // [0..17] = Weff, [18] = beff

  const int tid = threadIdx.x;

  // ---- zero LDS (halo ring must be 0 for pad=1 convs) ----
  for (int i = tid; i < 66 * LDSW; i += 1024) {
    ((float*)r_s)[i] = 0.f;
    ((float*)v_s)[i] = 0.f;
  }

  // ---- contract HID: Weff[ci,ky,kx] = sum_h Wr[h]*Wh[h,ci,ky,kx]; beff = Wr·bh ----
  if (tid < 19) {
    float acc = 0.f;
    if (tid < 18) {
      for (int h = 0; h < HID; ++h) acc += Wr[h] * Wh[h * 18 + tid];
    } else {
      for (int h = 0; h < HID; ++h) acc += Wr[h] * bh[h];
    }
    weff_s[tid] = acc;
  }
  __syncthreads();

  const int row  = tid >> 4;         // 0..63
  const int colb = (tid & 15) << 2;  // 0,4,...,60 : each thread owns 4 horiz cells

  // ---- stage 1: r(batch 0) = conv3x3(X[0], Weff) + beff ----
  {
    float wl[18];
    #pragma unroll
    for (int t = 0; t < 18; ++t) wl[t] = weff_s[t];
    const float beff = weff_s[18];
    #pragma unroll
    for (int j = 0; j < 4; ++j) {
      const int x = colb + j;
      float acc = beff;
      #pragma unroll
      for (int ci = 0; ci < 2; ++ci)
        #pragma unroll
        for (int dy = 0; dy < 3; ++dy) {
          const int y2 = row + dy - 1;
          #pragma unroll
          for (int dx = 0; dx < 3; ++dx) {
            const int x2 = x + dx - 1;
            const bool ok = (y2 >= 0) & (y2 < 64) & (x2 >= 0) & (x2 < 64);
            const float xv = ok ? X[ci * 4096 + y2 * 64 + x2] : 0.f;
            acc += wl[ci * 9 + dy * 3 + dx] * xv;
          }
        }
      r_s[row + 1][x + 1] = acc;
    }
  }
  __syncthreads();

  // ---- stage 2: qr[a][j] = conv3x3(r, Wq[a,0]) (iteration-invariant), v1 = max_a qr ----
  float qr[ACT][4];
  {
    float rn[3][6];
    #pragma unroll
    for (int dy = 0; dy < 3; ++dy)
      #pragma unroll
      for (int c = 0; c < 6; ++c)
        rn[dy][c] = r_s[row + dy][colb + c];

    float v1[4];
    #pragma unroll
    for (int a = 0; a < ACT; ++a) {
      float w[9];
      #pragma unroll
      for (int t = 0; t < 9; ++t) w[t] = Wq[a * 18 + t];   // uniform addr -> s_load
      #pragma unroll
      for (int j = 0; j < 4; ++j) {
        float acc = 0.f;
        #pragma unroll
        for (int dy = 0; dy < 3; ++dy)
          #pragma unroll
          for (int dx = 0; dx < 3; ++dx)
            acc += w[dy * 3 + dx] * rn[dy][j + dx];
        qr[a][j] = acc;
        v1[j] = (a == 0) ? acc : fmaxf(v1[j], acc);
      }
    }
    // v_s not read by anyone yet (zero-initialized) -> safe to write before sync
    #pragma unroll
    for (int j = 0; j < 4; ++j) v_s[row + 1][colb + j + 1] = v1[j];
  }
  __syncthreads();

  // ---- stage 3: 18 full VI updates (v2..v19): v' = max_a( qr[a] + conv3x3(v, Wq[a,1]) ) ----
  for (int it = 0; it < 18; ++it) {
    float vn[3][6];
    #pragma unroll
    for (int dy = 0; dy < 3; ++dy)
      #pragma unroll
      for (int c = 0; c < 6; ++c)
        vn[dy][c] = v_s[row + dy][colb + c];

    float vnew[4];
    #pragma unroll
    for (int a = 0; a < ACT; ++a) {
      float w[9];
      #pragma unroll
      for (int t = 0; t < 9; ++t) w[t] = Wq[a * 18 + 9 + t];  // uniform -> s_load
      #pragma unroll
      for (int j = 0; j < 4; ++j) {
        float acc = qr[a][j];
        #pragma unroll
        for (int dy = 0; dy < 3; ++dy)
          #pragma unroll
          for (int dx = 0; dx < 3; ++dx)
            acc += w[dy * 3 + dx] * vn[dy][j + dx];
        vnew[j] = (a == 0) ? acc : fmaxf(vnew[j], acc);
      }
    }
    __syncthreads();           // all reads of old v done
    #pragma unroll
    for (int j = 0; j < 4; ++j) v_s[row + 1][colb + j + 1] = vnew[j];
    __syncthreads();           // new v visible
  }

  // ---- stage 4: q20 at query points (recompute from r,v19 in LDS) + softmax over ACT ----
  if (tid < NK * ACT) {
    const int k = tid >> 3;
    const int a = tid & 7;
    const int y = S1[k];
    const int x = S2[k];
    float acc = 0.f;
    #pragma unroll
    for (int dy = 0; dy < 3; ++dy)
      #pragma unroll
      for (int dx = 0; dx < 3; ++dx) {
        const float w0 = Wq[a * 18 + dy * 3 + dx];
        const float w1 = Wq[a * 18 + 9 + dy * 3 + dx];
        acc += w0 * r_s[y + dy][x + dx] + w1 * v_s[y + dy][x + dx];
      }
    // softmax across the 8 lanes of this k-group (aligned groups of 8 within the wave)
    float m = acc;
    m = fmaxf(m, __shfl_xor(m, 1));
    m = fmaxf(m, __shfl_xor(m, 2));
    m = fmaxf(m, __shfl_xor(m, 4));
    const float e = __expf(acc - m);
    float s = e;
    s += __shfl_xor(s, 1);
    s += __shfl_xor(s, 2);
    s += __shfl_xor(s, 4);
    out[tid] = e / s;
  }
}

extern "C" void kernel_launch(void* const* d_in, const int* in_sizes, int n_in,
                              void* d_out, int out_size, void* d_ws, size_t ws_size,
                              hipStream_t stream) {
  const float* X  = (const float*)d_in[0];
  const int*   S1 = (const int*)d_in[1];
  const int*   S2 = (const int*)d_in[2];
  const float* Wh = (const float*)d_in[3];
  const float* bh = (const float*)d_in[4];
  const float* Wr = (const float*)d_in[5];
  const float* Wq = (const float*)d_in[6];
  float* out = (float*)d_out;

  vin_kernel<<<1, 1024, 0, stream>>>(X, S1, S2, Wh, bh, Wr, Wq, out);
}

// Round 2
// 136.645 us; speedup vs baseline: 1.0255x; 1.0255x over previous
//
#include <hip/hip_runtime.h>

// VIN, single CU (work is 19 sequential 64x64 convs -> ~0.3 MFLOP/step; grid
// sync would cost more than compute). Key levers this round:
//  - packed fp32 (v_pk_fma_f32 / v_pk_max_f32) via float2 elementwise builtins
//  - ping-pong v buffers: 1 barrier/iter instead of 2
//  - LDS stride 72 floats, interior at col offset 4 -> aligned b128 reads/writes
//  - __launch_bounds__(1024,4): allow 128 VGPR/wave so qr[8][2xv2f] stays resident

#define ACT 8
#define HID 150
#define NK  64
#define STR 72   // row stride (floats). interior cols 4..67, halo at 3 and 68.

typedef float v2f __attribute__((ext_vector_type(2)));

__device__ __forceinline__ v2f pkfma(v2f a, v2f b, v2f c) {
  return __builtin_elementwise_fma(a, b, c);
}
__device__ __forceinline__ v2f pkmax(v2f a, v2f b) {
  return __builtin_elementwise_max(a, b);
}

// row cells c0..c5 (cols colb+3 .. colb+8) -> overlapping pairs
// P[0]={c0,c1} P[1]={c1,c2} P[2]={c2,c3} P[3]={c3,c4} P[4]={c4,c5}
__device__ __forceinline__ void build_pairs(const float* rowp, int colb, v2f (&P)[5]) {
  const float4 own = *(const float4*)(rowp + colb + 4);   // 16B aligned
  const float eL = rowp[colb + 3];
  const float eR = rowp[colb + 8];
  P[0] = (v2f){eL,    own.x};
  P[1] = (v2f){own.x, own.y};
  P[2] = (v2f){own.y, own.z};
  P[3] = (v2f){own.z, own.w};
  P[4] = (v2f){own.w, eR};
}

__device__ __forceinline__ void vi_step(const float (*src)[STR], float (*dst)[STR],
                                        const v2f (&qr)[ACT][2],
                                        const float* __restrict__ Wq,
                                        int row, int colb) {
  v2f P[3][5];
  #pragma unroll
  for (int dy = 0; dy < 3; ++dy) build_pairs(&src[row + dy][0], colb, P[dy]);

  v2f m0, m1;
  #pragma unroll
  for (int a = 0; a < ACT; ++a) {
    v2f acc0 = qr[a][0];
    v2f acc1 = qr[a][1];
    #pragma unroll
    for (int dy = 0; dy < 3; ++dy)
      #pragma unroll
      for (int dx = 0; dx < 3; ++dx) {
        const float w = Wq[a * 18 + 9 + dy * 3 + dx];  // uniform -> SGPR
        const v2f w2 = {w, w};
        acc0 = pkfma(w2, P[dy][dx],     acc0);
        acc1 = pkfma(w2, P[dy][dx + 2], acc1);
      }
    m0 = a ? pkmax(m0, acc0) : acc0;
    m1 = a ? pkmax(m1, acc1) : acc1;
  }
  *(float4*)&dst[row + 1][colb + 4] = make_float4(m0.x, m0.y, m1.x, m1.y);
  __syncthreads();
}

__launch_bounds__(1024, 4)
__global__ void vin_kernel(const float* __restrict__ X,
                           const int*   __restrict__ S1,
                           const int*   __restrict__ S2,
                           const float* __restrict__ Wh,
                           const float* __restrict__ bh,
                           const float* __restrict__ Wr,
                           const float* __restrict__ Wq,
                           float*       __restrict__ out) {
  __shared__ float r_s[66][STR];
  __shared__ float v_s[2][66][STR];
  __shared__ float weff_s[20];   // [0..17]=Weff, [18]=beff

  const int tid = threadIdx.x;

  // zero LDS (halo ring must stay 0 for pad=1 convs; v_s[1] halo never rewritten)
  for (int i = tid; i < 66 * STR; i += 1024)      ((float*)r_s)[i] = 0.f;
  for (int i = tid; i < 2 * 66 * STR; i += 1024)  ((float*)v_s)[i] = 0.f;

  // contract HID: Weff = sum_h Wr[h]*Wh[h,:,:,:]; beff = Wr.bh
  if (tid < 19) {
    float acc = 0.f;
    if (tid < 18) { for (int h = 0; h < HID; ++h) acc += Wr[h] * Wh[h * 18 + tid]; }
    else          { for (int h = 0; h < HID; ++h) acc += Wr[h] * bh[h]; }
    weff_s[tid] = acc;
  }
  __syncthreads();

  const int row  = tid >> 4;          // 0..63
  const int colb = (tid & 15) << 2;   // 0,4,...,60

  // ---- stage 1: r(batch 0) = conv3x3(X[0], Weff) + beff ----
  {
    float wl[18];
    #pragma unroll
    for (int t = 0; t < 18; ++t) wl[t] = weff_s[t];
    const float beff = weff_s[18];
    #pragma unroll
    for (int j = 0; j < 4; ++j) {
      const int x = colb + j;
      float acc = beff;
      #pragma unroll
      for (int ci = 0; ci < 2; ++ci)
        #pragma unroll
        for (int dy = 0; dy < 3; ++dy) {
          const int y2 = row + dy - 1;
          #pragma unroll
          for (int dx = 0; dx < 3; ++dx) {
            const int x2 = x + dx - 1;
            const bool ok = (y2 >= 0) & (y2 < 64) & (x2 >= 0) & (x2 < 64);
            const float xv = ok ? X[ci * 4096 + y2 * 64 + x2] : 0.f;
            acc += wl[ci * 9 + dy * 3 + dx] * xv;
          }
        }
      r_s[row + 1][x + 4] = acc;
    }
  }
  __syncthreads();

  // ---- stage 2: qr = conv3x3(r, Wq[:,0]) (iteration-invariant); v1 = max_a qr ----
  v2f qr[ACT][2];
  {
    v2f P[3][5];
    #pragma unroll
    for (int dy = 0; dy < 3; ++dy) build_pairs(&r_s[row + dy][0], colb, P[dy]);

    v2f m0, m1;
    #pragma unroll
    for (int a = 0; a < ACT; ++a) {
      v2f acc0 = (v2f){0.f, 0.f};
      v2f acc1 = (v2f){0.f, 0.f};
      #pragma unroll
      for (int dy = 0; dy < 3; ++dy)
        #pragma unroll
        for (int dx = 0; dx < 3; ++dx) {
          const float w = Wq[a * 18 + dy * 3 + dx];
          const v2f w2 = {w, w};
          acc0 = pkfma(w2, P[dy][dx],     acc0);
          acc1 = pkfma(w2, P[dy][dx + 2], acc1);
        }
      qr[a][0] = acc0;
      qr[a][1] = acc1;
      m0 = a ? pkmax(m0, acc0) : acc0;
      m1 = a ? pkmax(m1, acc1) : acc1;
    }
    *(float4*)&v_s[0][row + 1][colb + 4] = make_float4(m0.x, m0.y, m1.x, m1.y);
  }
  __syncthreads();

  // ---- stage 3: 18 full VI updates, ping-pong v_s[0] <-> v_s[1] ----
  for (int it = 0; it < 9; ++it) {
    vi_step(v_s[0], v_s[1], qr, Wq, row, colb);
    vi_step(v_s[1], v_s[0], qr, Wq, row, colb);
  }
  // final v19 in v_s[0]

  // ---- stage 4: q20 at query points + softmax over ACT ----
  if (tid < NK * ACT) {
    const int k = tid >> 3;
    const int a = tid & 7;
    const int y = S1[k];
    const int x = S2[k];
    float acc = 0.f;
    #pragma unroll
    for (int dy = 0; dy < 3; ++dy)
      #pragma unroll
      for (int dx = 0; dx < 3; ++dx) {
        const float w0 = Wq[a * 18 + dy * 3 + dx];
        const float w1 = Wq[a * 18 + 9 + dy * 3 + dx];
        acc += w0 * r_s[y + dy][x + dx + 3] + w1 * v_s[0][y + dy][x + dx + 3];
      }
    float m = acc;
    m = fmaxf(m, __shfl_xor(m, 1));
    m = fmaxf(m, __shfl_xor(m, 2));
    m = fmaxf(m, __shfl_xor(m, 4));
    const float e = __expf(acc - m);
    float s = e;
    s += __shfl_xor(s, 1);
    s += __shfl_xor(s, 2);
    s += __shfl_xor(s, 4);
    out[tid] = e / s;
  }
}

extern "C" void kernel_launch(void* const* d_in, const int* in_sizes, int n_in,
                              void* d_out, int out_size, void* d_ws, size_t ws_size,
                              hipStream_t stream) {
  const float* X  = (const float*)d_in[0];
  const int*   S1 = (const int*)d_in[1];
  const int*   S2 = (const int*)d_in[2];
  const float* Wh = (const float*)d_in[3];
  const float* bh = (const float*)d_in[4];
  const float* Wr = (const float*)d_in[5];
  const float* Wq = (const float*)d_in[6];
  float* out = (float*)d_out;

  vin_kernel<<<1, 1024, 0, stream>>>(X, S1, S2, Wh, bh, Wr, Wq, out);
}